// Round 7
// baseline (749.371 us; speedup 1.0000x reference)
//
#include <hip/hip_runtime.h>

typedef __bf16 bf16x8 __attribute__((ext_vector_type(8)));
typedef float f32x4 __attribute__((ext_vector_type(4)));

#define T_LEN 200
#define NB 4096
#define RPB 8   // batch rows per block (M-tile half-used; trades MFMA width for 2 waves/SIMD)

__device__ __forceinline__ f32x4 mfma16(bf16x8 a, bf16x8 b, f32x4 c) {
    return __builtin_amdgcn_mfma_f32_16x16x32_bf16(a, b, c, 0, 0, 0);
}
__device__ __forceinline__ float sigf(float x) { return 1.0f / (1.0f + __expf(-x)); }
__device__ __forceinline__ float tanh_fast(float x) {
    x = fminf(15.0f, fmaxf(-15.0f, x));
    float e = __expf(2.0f * x);
    return (e - 1.0f) / (e + 1.0f);
}

// A-side fragments keep bf16 hi/lo split (x, h, rh); B-side (weights) is bf16-hi only.
struct Frag { bf16x8 hi, lo; };

__device__ __forceinline__ Frag make_frag(f32x4 a, f32x4 b) {
    Frag f;
    #pragma unroll
    for (int j = 0; j < 4; j++) {
        float v = a[j]; __bf16 h = (__bf16)v;
        f.hi[j] = h; f.lo[j] = (__bf16)(v - (float)h);
    }
    #pragma unroll
    for (int j = 0; j < 4; j++) {
        float v = b[j]; __bf16 h = (__bf16)v;
        f.hi[4 + j] = h; f.lo[4 + j] = (__bf16)(v - (float)h);
    }
    return f;
}
__device__ __forceinline__ bf16x8 load_w(const float* p) {
    f32x4 a = *(const f32x4*)p, b = *(const f32x4*)(p + 4);
    bf16x8 w;
    #pragma unroll
    for (int j = 0; j < 4; j++) { w[j] = (__bf16)a[j]; w[4 + j] = (__bf16)b[j]; }
    return w;
}
// acc += (A.hi + A.lo) * W   (W bf16-rounded)
__device__ __forceinline__ f32x4 mm2(Frag a, bf16x8 w, f32x4 acc) {
    acc = mfma16(a.hi, w, acc);
    acc = mfma16(a.lo, w, acc);
    return acc;
}

__global__ __launch_bounds__(256, 2)
void dien_fused(const int* __restrict__ u_idx, const int* __restrict__ i_idx,
                const int* __restrict__ seq, const float* __restrict__ item_emb,
                const float* __restrict__ user_bias, const float* __restrict__ item_bias,
                const float* __restrict__ gw_ih, const float* __restrict__ gb_ih,
                const float* __restrict__ gw_hh, const float* __restrict__ gb_hh,
                const float* __restrict__ attn_w, const float* __restrict__ attn_b,
                const float* __restrict__ wr_w, const float* __restrict__ wr_b,
                const float* __restrict__ wz_w, const float* __restrict__ wz_b,
                const float* __restrict__ wh_w, const float* __restrict__ wh_b,
                const float* __restrict__ aux_w, const float* __restrict__ aux_b,
                float* __restrict__ out)
{
    __shared__ int sSeq[RPB][T_LEN];
    __shared__ __align__(16) float sTP[16][64];
    __shared__ __align__(16) __bf16 sHGhi[16][72], sHGlo[16][72];
    __shared__ __align__(16) __bf16 sHAhi[16][72], sHAlo[16][72];
    __shared__ __align__(16) __bf16 sRHhi[16][72], sRHlo[16][72];
    __shared__ __align__(16) float sParts[16][4];

    const int tid  = threadIdx.x;
    const int wave = tid >> 6;
    const int lane = tid & 63;
    const int c    = lane & 15;        // A-row / C-col index (rows >= RPB are dummy)
    const int q    = lane >> 4;        // quad
    const int row0 = blockIdx.x * RPB; // batch rows [row0, row0+RPB)
    const int dglob = wave * 16 + c;   // this lane's output feature d in [0,64)
    const int cmod  = c & (RPB - 1);   // valid row for dummy A-rows

    // ---- stage seq indices (RPB valid rows) ----
    for (int i = tid; i < RPB * T_LEN; i += 256) {
        int b = i / T_LEN, t = i - b * T_LEN;
        sSeq[b][t] = seq[(row0 + b) * T_LEN + t];
    }

    // ---- fm1 ----
    if (tid < RPB) {
        int b = row0 + tid;
        out[b] = user_bias[u_idx[b]] + item_bias[i_idx[b]];
    }

    // ---- target_proj (rows >= RPB duplicate row b&7; harmless) ----
    {
        int b  = tid >> 4;
        int d0 = (tid & 15) * 4;
        const float* erow = item_emb + (long)i_idx[row0 + (b & (RPB - 1))] * 64;
        float e[64];
        #pragma unroll
        for (int k4 = 0; k4 < 16; k4++) {
            f32x4 v = *(const f32x4*)(erow + k4 * 4);
            #pragma unroll
            for (int j = 0; j < 4; j++) e[k4 * 4 + j] = v[j];
        }
        #pragma unroll
        for (int dd = 0; dd < 4; dd++) {
            int d = d0 + dd;
            const float* wrow = attn_w + d * 64;
            float s = attn_b[d];
            #pragma unroll
            for (int k4 = 0; k4 < 16; k4++) {
                f32x4 wv = *(const f32x4*)(wrow + k4 * 4);
                #pragma unroll
                for (int j = 0; j < 4; j++) s += e[k4 * 4 + j] * wv[j];
            }
            sTP[b][d] = s;
        }
    }

    // ---- zero h_aug exchange buffers ----
    for (int i = tid; i < 16 * 72; i += 256) {
        ((__bf16*)sHAhi)[i] = (__bf16)0.0f;
        ((__bf16*)sHAlo)[i] = (__bf16)0.0f;
    }
    __syncthreads();

    // ---- register-resident weight B-fragments (bf16-hi only) ----
    bf16x8 wih[3][2], whh[3][2];
    #pragma unroll
    for (int g = 0; g < 3; g++) {
        int f = g * 64 + dglob;
        #pragma unroll
        for (int s = 0; s < 2; s++) {
            wih[g][s] = load_w(gw_ih + f * 64 + s * 32 + q * 8);
            whh[g][s] = load_w(gw_hh + f * 64 + s * 32 + q * 8);
        }
    }
    bf16x8 wrx[2], wrh[2], wzx[2], wzh[2], whx[2], whhat[2];
    #pragma unroll
    for (int s = 0; s < 2; s++) {
        const int fo = dglob * 128 + s * 32 + q * 8;
        wrx[s]   = load_w(wr_w + fo);
        wrh[s]   = load_w(wr_w + fo + 64);
        wzx[s]   = load_w(wz_w + fo);
        wzh[s]   = load_w(wz_w + fo + 64);
        whx[s]   = load_w(wh_w + fo);
        whhat[s] = load_w(wh_w + fo + 64);
    }

    // ---- per-lane biases (feature = dglob), accumulator inits ----
    const float bR  = gb_ih[dglob]       + gb_hh[dglob];
    const float bZ  = gb_ih[64 + dglob]  + gb_hh[64 + dglob];
    const float bNX = gb_ih[128 + dglob];
    const float bNH = gb_hh[128 + dglob];
    const float bAR = wr_b[dglob];
    const float bAZ = wz_b[dglob];
    const float bAH = wh_b[dglob];
    const float auxwc = aux_w[dglob];

    float tp_c[4];
    #pragma unroll
    for (int i = 0; i < 4; i++) tp_c[i] = sTP[q * 4 + i][dglob];

    // ---- state ----
    float hg_c[4] = {0.f, 0.f, 0.f, 0.f};
    float ha_c[4] = {0.f, 0.f, 0.f, 0.f};
    Frag hgf[2];
    #pragma unroll
    for (int s = 0; s < 2; s++)
        #pragma unroll
        for (int j = 0; j < 8; j++) { hgf[s].hi[j] = (__bf16)0.f; hgf[s].lo[j] = (__bf16)0.f; }

    // ---- prefetch x for t=0 (dummy rows use row cmod) ----
    const float* ep0 = item_emb + (long)sSeq[cmod][0] * 64 + q * 8;
    f32x4 xa0 = *(const f32x4*)ep0, xa1 = *(const f32x4*)(ep0 + 4);
    f32x4 xb0 = *(const f32x4*)(ep0 + 32), xb1 = *(const f32x4*)(ep0 + 36);

    for (int t = 0; t < T_LEN; t++) {
        Frag xA[2];
        xA[0] = make_frag(xa0, xa1);
        xA[1] = make_frag(xb0, xb1);
        // prefetch t+1
        int tn = (t + 1 < T_LEN) ? t + 1 : t;
        const float* ep = item_emb + (long)sSeq[cmod][tn] * 64 + q * 8;
        xa0 = *(const f32x4*)ep;  xa1 = *(const f32x4*)(ep + 4);
        xb0 = *(const f32x4*)(ep + 32); xb1 = *(const f32x4*)(ep + 36);

        // h_aug A-frags (written end of prev iter, after barrier2)
        Frag haf[2];
        haf[0].hi = *(const bf16x8*)&sHAhi[c][q * 8];
        haf[1].hi = *(const bf16x8*)&sHAhi[c][32 + q * 8];
        haf[0].lo = *(const bf16x8*)&sHAlo[c][q * 8];
        haf[1].lo = *(const bf16x8*)&sHAlo[c][32 + q * 8];

        // ---- projections (bias-preloaded accumulators) ----
        f32x4 accR = {bR, bR, bR, bR};
        accR = mm2(xA[0], wih[0][0], accR); accR = mm2(xA[1], wih[0][1], accR);
        accR = mm2(hgf[0], whh[0][0], accR); accR = mm2(hgf[1], whh[0][1], accR);
        f32x4 accZ = {bZ, bZ, bZ, bZ};
        accZ = mm2(xA[0], wih[1][0], accZ); accZ = mm2(xA[1], wih[1][1], accZ);
        accZ = mm2(hgf[0], whh[1][0], accZ); accZ = mm2(hgf[1], whh[1][1], accZ);
        f32x4 accNX = {bNX, bNX, bNX, bNX};
        accNX = mm2(xA[0], wih[2][0], accNX); accNX = mm2(xA[1], wih[2][1], accNX);
        f32x4 accNH = {bNH, bNH, bNH, bNH};
        accNH = mm2(hgf[0], whh[2][0], accNH); accNH = mm2(hgf[1], whh[2][1], accNH);

        f32x4 accAR = {bAR, bAR, bAR, bAR};
        accAR = mm2(xA[0], wrx[0], accAR); accAR = mm2(xA[1], wrx[1], accAR);
        accAR = mm2(haf[0], wrh[0], accAR); accAR = mm2(haf[1], wrh[1], accAR);
        f32x4 accAZ = {bAZ, bAZ, bAZ, bAZ};
        accAZ = mm2(xA[0], wzx[0], accAZ); accAZ = mm2(xA[1], wzx[1], accAZ);
        accAZ = mm2(haf[0], wzh[0], accAZ); accAZ = mm2(haf[1], wzh[1], accAZ);
        f32x4 accAH = {bAH, bAH, bAH, bAH};
        accAH = mm2(xA[0], whx[0], accAH); accAH = mm2(xA[1], whx[1], accAH);

        // ---- GRU gating -> h_gru_t; attn-score partials ----
        float pr[4];
        #pragma unroll
        for (int i = 0; i < 4; i++) {
            float r = sigf(accR[i]);
            float z = sigf(accZ[i]);
            float n = tanh_fast(accNX[i] + r * accNH[i]);
            float hn = (1.0f - z) * n + z * hg_c[i];
            hg_c[i] = hn;
            __bf16 hi = (__bf16)hn;
            int rr = q * 4 + i;
            sHGhi[rr][dglob] = hi;
            sHGlo[rr][dglob] = (__bf16)(hn - (float)hi);
            pr[i] = hn * tp_c[i];
        }
        #pragma unroll
        for (int m = 1; m < 16; m <<= 1) {
            #pragma unroll
            for (int i = 0; i < 4; i++) pr[i] += __shfl_xor(pr[i], m, 64);
        }
        if (c == 0) {
            #pragma unroll
            for (int i = 0; i < 4; i++) sParts[q * 4 + i][wave] = pr[i];
        }

        // ---- AUGRU r,z gating; rh = r*h_aug ----
        float z_c[4];
        #pragma unroll
        for (int i = 0; i < 4; i++) {
            float r = sigf(accAR[i]);
            z_c[i]  = sigf(accAZ[i]);
            float rh = r * ha_c[i];
            __bf16 hi = (__bf16)rh;
            int rr = q * 4 + i;
            sRHhi[rr][dglob] = hi;
            sRHlo[rr][dglob] = (__bf16)(rh - (float)hi);
        }

        __syncthreads();  // barrier 1

        hgf[0].hi = *(const bf16x8*)&sHGhi[c][q * 8];
        hgf[1].hi = *(const bf16x8*)&sHGhi[c][32 + q * 8];
        hgf[0].lo = *(const bf16x8*)&sHGlo[c][q * 8];
        hgf[1].lo = *(const bf16x8*)&sHGlo[c][32 + q * 8];
        Frag rhf[2];
        rhf[0].hi = *(const bf16x8*)&sRHhi[c][q * 8];
        rhf[1].hi = *(const bf16x8*)&sRHhi[c][32 + q * 8];
        rhf[0].lo = *(const bf16x8*)&sRHlo[c][q * 8];
        rhf[1].lo = *(const bf16x8*)&sRHlo[c][32 + q * 8];

        accAH = mm2(rhf[0], whhat[0], accAH);
        accAH = mm2(rhf[1], whhat[1], accAH);

        #pragma unroll
        for (int i = 0; i < 4; i++) {
            int rr = q * 4 + i;
            float a = sigf(sParts[rr][0] + sParts[rr][1] + sParts[rr][2] + sParts[rr][3]);
            float zz = a * z_c[i];
            float hh = tanh_fast(accAH[i]);
            float hv = (1.0f - zz) * ha_c[i] + zz * hh;
            ha_c[i] = hv;
            __bf16 hi = (__bf16)hv;
            sHAhi[rr][dglob] = hi;
            sHAlo[rr][dglob] = (__bf16)(hv - (float)hi);
        }

        __syncthreads();  // barrier 2
    }

    // ---- attn_vec (only valid rows) ----
    #pragma unroll
    for (int i = 0; i < 4; i++) {
        int rr = q * 4 + i;
        if (rr < RPB) out[NB + (row0 + rr) * 64 + dglob] = ha_c[i];
    }

    // ---- aux_logits ----
    float pa[4];
    #pragma unroll
    for (int i = 0; i < 4; i++) pa[i] = hg_c[i] * auxwc;
    #pragma unroll
    for (int m = 1; m < 16; m <<= 1) {
        #pragma unroll
        for (int i = 0; i < 4; i++) pa[i] += __shfl_xor(pa[i], m, 64);
    }
    if (c == 0) {
        #pragma unroll
        for (int i = 0; i < 4; i++) sParts[q * 4 + i][wave] = pa[i];
    }
    __syncthreads();
    if (tid < RPB) {
        out[NB + NB * 64 + row0 + tid] =
            sParts[tid][0] + sParts[tid][1] + sParts[tid][2] + sParts[tid][3] + aux_b[0];
    }
}

extern "C" void kernel_launch(void* const* d_in, const int* in_sizes, int n_in,
                              void* d_out, int out_size, void* d_ws, size_t ws_size,
                              hipStream_t stream) {
    dien_fused<<<dim3(NB / RPB), dim3(256), 0, stream>>>(
        (const int*)d_in[0],      // u_idx
        (const int*)d_in[1],      // i_idx
        (const int*)d_in[2],      // seq
        (const float*)d_in[3],    // item_emb
        (const float*)d_in[4],    // user_bias
        (const float*)d_in[5],    // item_bias
        (const float*)d_in[6],    // gru_w_ih
        (const float*)d_in[7],    // gru_b_ih
        (const float*)d_in[8],    // gru_w_hh
        (const float*)d_in[9],    // gru_b_hh
        (const float*)d_in[10],   // attn_w
        (const float*)d_in[11],   // attn_b
        (const float*)d_in[12],   // wr_w
        (const float*)d_in[13],   // wr_b
        (const float*)d_in[14],   // wz_w
        (const float*)d_in[15],   // wz_b
        (const float*)d_in[16],   // wh_w
        (const float*)d_in[17],   // wh_b
        (const float*)d_in[18],   // aux_w
        (const float*)d_in[19],   // aux_b
        (float*)d_out);
}

// Round 8
// 513.330 us; speedup vs baseline: 1.4598x; 1.4598x over previous
//
#include <hip/hip_runtime.h>

typedef __bf16 bf16x8 __attribute__((ext_vector_type(8)));
typedef float f32x4 __attribute__((ext_vector_type(4)));

#define T_LEN 200
#define NB 4096

__device__ __forceinline__ f32x4 mfma16(bf16x8 a, bf16x8 b, f32x4 c) {
    return __builtin_amdgcn_mfma_f32_16x16x32_bf16(a, b, c, 0, 0, 0);
}
__device__ __forceinline__ float sigf(float x) { return 1.0f / (1.0f + __expf(-x)); }
__device__ __forceinline__ float tanh_fast(float x) {
    x = fminf(15.0f, fmaxf(-15.0f, x));
    float e = __expf(2.0f * x);
    return (e - 1.0f) / (e + 1.0f);
}

// bf16 hi/lo split fragment (fp32-accurate MFMA inputs)
struct Frag { bf16x8 hi, lo; };

__device__ __forceinline__ Frag make_frag(f32x4 a, f32x4 b) {
    Frag f;
    #pragma unroll
    for (int j = 0; j < 4; j++) {
        float v = a[j]; __bf16 h = (__bf16)v;
        f.hi[j] = h; f.lo[j] = (__bf16)(v - (float)h);
    }
    #pragma unroll
    for (int j = 0; j < 4; j++) {
        float v = b[j]; __bf16 h = (__bf16)v;
        f.hi[4 + j] = h; f.lo[4 + j] = (__bf16)(v - (float)h);
    }
    return f;
}
__device__ __forceinline__ Frag load_split(const float* p) {
    return make_frag(*(const f32x4*)p, *(const f32x4*)(p + 4));
}
// acc += A*B with hi/lo 3-term product (drops lo*lo ~ 2^-18)
__device__ __forceinline__ f32x4 mm3(Frag a, Frag b, f32x4 acc) {
    acc = mfma16(a.hi, b.hi, acc);
    acc = mfma16(a.hi, b.lo, acc);
    acc = mfma16(a.lo, b.hi, acc);
    return acc;
}

// 8 waves/block: waves 0-3 = GRU group (G), waves 4-7 = AUGRU group (A).
// AUGRU is pipelined one step: ha(t) is finalized in iteration t+1 section 0.
// LDS hazard audit (all producer->consumer pairs cross >=1 barrier):
//   sHG : W by G in S0(t), R by G in S1(t)          [b_mid between]
//   sRH : W by A in S1(t), R by A in S0(t+1)/epilog [b_end between]
//   sHA : W by A in S0(t), R by A in S1(t)          [b_mid between]
//   sParts[p]: W by G in S0(t) (p=t&1), R by A in S0(t+1) (p=t&1) [2 barriers]
__global__ __launch_bounds__(512, 2)
void dien_fused(const int* __restrict__ u_idx, const int* __restrict__ i_idx,
                const int* __restrict__ seq, const float* __restrict__ item_emb,
                const float* __restrict__ user_bias, const float* __restrict__ item_bias,
                const float* __restrict__ gw_ih, const float* __restrict__ gb_ih,
                const float* __restrict__ gw_hh, const float* __restrict__ gb_hh,
                const float* __restrict__ attn_w, const float* __restrict__ attn_b,
                const float* __restrict__ wr_w, const float* __restrict__ wr_b,
                const float* __restrict__ wz_w, const float* __restrict__ wz_b,
                const float* __restrict__ wh_w, const float* __restrict__ wh_b,
                const float* __restrict__ aux_w, const float* __restrict__ aux_b,
                float* __restrict__ out)
{
    __shared__ int sSeq[16][T_LEN];
    __shared__ __align__(16) float sTP[16][64];
    __shared__ __align__(16) __bf16 sHGhi[16][72], sHGlo[16][72];
    __shared__ __align__(16) __bf16 sHAhi[16][72], sHAlo[16][72];
    __shared__ __align__(16) __bf16 sRHhi[16][72], sRHlo[16][72];
    __shared__ __align__(16) float sParts[2][16][4];

    const int tid  = threadIdx.x;
    const int wave = tid >> 6;           // 0..7
    const int lane = tid & 63;
    const int c    = lane & 15;          // A-row / C-col index
    const int q    = lane >> 4;          // quad
    const bool isG = (wave < 4);
    const int wg   = wave & 3;           // wave id within group
    const int dglob = wg * 16 + c;       // output feature d in [0,64)
    const int row0 = blockIdx.x * 16;

    // ---- stage seq indices ----
    for (int i = tid; i < 16 * T_LEN; i += 512) {
        int b = i / T_LEN, t = i - b * T_LEN;
        sSeq[b][t] = seq[(row0 + b) * T_LEN + t];
    }

    // ---- fm1 ----
    if (tid < 16) {
        int b = row0 + tid;
        out[b] = user_bias[u_idx[b]] + item_bias[i_idx[b]];
    }

    // ---- target_proj (16x64 fp32), threads 0..255 ----
    if (tid < 256) {
        int b  = tid >> 4;
        int d0 = (tid & 15) * 4;
        const float* erow = item_emb + (long)i_idx[row0 + b] * 64;
        float e[64];
        #pragma unroll
        for (int k4 = 0; k4 < 16; k4++) {
            f32x4 v = *(const f32x4*)(erow + k4 * 4);
            #pragma unroll
            for (int j = 0; j < 4; j++) e[k4 * 4 + j] = v[j];
        }
        #pragma unroll
        for (int dd = 0; dd < 4; dd++) {
            int d = d0 + dd;
            const float* wrow = attn_w + d * 64;
            float s = attn_b[d];
            #pragma unroll
            for (int k4 = 0; k4 < 16; k4++) {
                f32x4 wv = *(const f32x4*)(wrow + k4 * 4);
                #pragma unroll
                for (int j = 0; j < 4; j++) s += e[k4 * 4 + j] * wv[j];
            }
            sTP[b][d] = s;
        }
    }

    // ---- zero ha exchange buffer (t=0 S1 reads it) ----
    for (int i = tid; i < 16 * 72; i += 512) {
        ((__bf16*)sHAhi)[i] = (__bf16)0.0f;
        ((__bf16*)sHAlo)[i] = (__bf16)0.0f;
    }
    __syncthreads();

    // ---- register-resident weights, hi/lo split, UNIONED across groups ----
    // G: W[0..5]=wih[g][s] (g*2+s), W[6..11]=whh[g][s]
    // A: W[0..1]=wrx, W[2..3]=wrh, W[4..5]=wzx, W[6..7]=wzh, W[8..9]=whx, W[10..11]=whhat
    Frag W[12];
    if (isG) {
        #pragma unroll
        for (int g = 0; g < 3; g++)
            #pragma unroll
            for (int s = 0; s < 2; s++) {
                W[g * 2 + s]     = load_split(gw_ih + (g * 64 + dglob) * 64 + s * 32 + q * 8);
                W[6 + g * 2 + s] = load_split(gw_hh + (g * 64 + dglob) * 64 + s * 32 + q * 8);
            }
    } else {
        #pragma unroll
        for (int s = 0; s < 2; s++) {
            const int fo = dglob * 128 + s * 32 + q * 8;
            W[0 + s]  = load_split(wr_w + fo);
            W[2 + s]  = load_split(wr_w + fo + 64);
            W[4 + s]  = load_split(wz_w + fo);
            W[6 + s]  = load_split(wz_w + fo + 64);
            W[8 + s]  = load_split(wh_w + fo);
            W[10 + s] = load_split(wh_w + fo + 64);
        }
    }

    // ---- per-lane biases (path-dependent meaning) ----
    float bA, bB, bC, bD;
    if (isG) {
        bA = gb_ih[dglob] + gb_hh[dglob];             // r gate
        bB = gb_ih[64 + dglob] + gb_hh[64 + dglob];   // z gate
        bC = gb_ih[128 + dglob];                       // n, x part
        bD = gb_hh[128 + dglob];                       // n, h part
    } else {
        bA = wr_b[dglob];
        bB = wz_b[dglob];
        bC = wh_b[dglob];
        bD = 0.0f;
    }
    const float auxwc = aux_w[dglob];

    float tp_c[4] = {0.f, 0.f, 0.f, 0.f};
    if (isG) {
        #pragma unroll
        for (int i = 0; i < 4; i++) tp_c[i] = sTP[q * 4 + i][dglob];
    }

    // ---- state ----
    float hst[4] = {0.f, 0.f, 0.f, 0.f};  // G: hg(t) ; A: ha(t-1) (C-layout)
    Frag fr[2];                            // G: hgf(t-1) ; A: haf scratch
    #pragma unroll
    for (int s = 0; s < 2; s++)
        #pragma unroll
        for (int j = 0; j < 8; j++) { fr[s].hi[j] = (__bf16)0.f; fr[s].lo[j] = (__bf16)0.f; }
    f32x4 aAH = {0.f, 0.f, 0.f, 0.f};      // A: carries xh-part of h_hat(t) into iter t+1
    float z_c[4] = {0.f, 0.f, 0.f, 0.f};   // A: z(t) carried into iter t+1

    // ---- prefetch x(0) ----
    const float* ep0 = item_emb + (long)sSeq[c][0] * 64 + q * 8;
    f32x4 xa0 = *(const f32x4*)ep0, xa1 = *(const f32x4*)(ep0 + 4);
    f32x4 xb0 = *(const f32x4*)(ep0 + 32), xb1 = *(const f32x4*)(ep0 + 36);

    for (int t = 0; t < T_LEN; t++) {
        Frag xA0 = make_frag(xa0, xa1);
        Frag xA1 = make_frag(xb0, xb1);
        int tn = (t + 1 < T_LEN) ? t + 1 : t;
        const float* ep = item_emb + (long)sSeq[c][tn] * 64 + q * 8;
        xa0 = *(const f32x4*)ep;        xa1 = *(const f32x4*)(ep + 4);
        xb0 = *(const f32x4*)(ep + 32); xb1 = *(const f32x4*)(ep + 36);

        f32x4 aAR, aAZ;  // A-group: r/z preactivations, live S0 -> S1

        // ================= Section 0 (pre-b_mid) =================
        if (isG) {
            f32x4 accR = {bA, bA, bA, bA};
            accR = mm3(xA0, W[0], accR); accR = mm3(xA1, W[1], accR);
            accR = mm3(fr[0], W[6], accR); accR = mm3(fr[1], W[7], accR);
            f32x4 accZ = {bB, bB, bB, bB};
            accZ = mm3(xA0, W[2], accZ); accZ = mm3(xA1, W[3], accZ);
            accZ = mm3(fr[0], W[8], accZ); accZ = mm3(fr[1], W[9], accZ);
            f32x4 accNX = {bC, bC, bC, bC};
            accNX = mm3(xA0, W[4], accNX); accNX = mm3(xA1, W[5], accNX);
            f32x4 accNH = {bD, bD, bD, bD};
            accNH = mm3(fr[0], W[10], accNH); accNH = mm3(fr[1], W[11], accNH);

            float pr[4];
            #pragma unroll
            for (int i = 0; i < 4; i++) {
                float r = sigf(accR[i]);
                float z = sigf(accZ[i]);
                float n = tanh_fast(accNX[i] + r * accNH[i]);
                float hn = (1.0f - z) * n + z * hst[i];
                hst[i] = hn;
                __bf16 hi = (__bf16)hn;
                int rr = q * 4 + i;
                sHGhi[rr][dglob] = hi;
                sHGlo[rr][dglob] = (__bf16)(hn - (float)hi);
                pr[i] = hn * tp_c[i];
            }
            #pragma unroll
            for (int m = 1; m < 16; m <<= 1) {
                #pragma unroll
                for (int i = 0; i < 4; i++) pr[i] += __shfl_xor(pr[i], m, 64);
            }
            if (c == 0) {
                #pragma unroll
                for (int i = 0; i < 4; i++) sParts[t & 1][q * 4 + i][wg] = pr[i];
            }
        } else {
            if (t > 0) {
                // finalize ha(t-1): rh-part of h_hat, attention gate, blend
                Frag rh0, rh1;
                rh0.hi = *(const bf16x8*)&sRHhi[c][q * 8];
                rh1.hi = *(const bf16x8*)&sRHhi[c][32 + q * 8];
                rh0.lo = *(const bf16x8*)&sRHlo[c][q * 8];
                rh1.lo = *(const bf16x8*)&sRHlo[c][32 + q * 8];
                aAH = mm3(rh0, W[10], aAH); aAH = mm3(rh1, W[11], aAH);
                #pragma unroll
                for (int i = 0; i < 4; i++) {
                    int rr = q * 4 + i;
                    float a = sigf(sParts[(t - 1) & 1][rr][0] + sParts[(t - 1) & 1][rr][1] +
                                   sParts[(t - 1) & 1][rr][2] + sParts[(t - 1) & 1][rr][3]);
                    float hh = tanh_fast(aAH[i]);
                    float zz = a * z_c[i];
                    float hv = (1.0f - zz) * hst[i] + zz * hh;
                    hst[i] = hv;
                    __bf16 hi = (__bf16)hv;
                    sHAhi[rr][dglob] = hi;
                    sHAlo[rr][dglob] = (__bf16)(hv - (float)hi);
                }
            }
            // x-parts of step t
            aAR = (f32x4){bA, bA, bA, bA};
            aAR = mm3(xA0, W[0], aAR); aAR = mm3(xA1, W[1], aAR);
            aAZ = (f32x4){bB, bB, bB, bB};
            aAZ = mm3(xA0, W[4], aAZ); aAZ = mm3(xA1, W[5], aAZ);
            aAH = (f32x4){bC, bC, bC, bC};
            aAH = mm3(xA0, W[8], aAH); aAH = mm3(xA1, W[9], aAH);
        }

        __syncthreads();  // b_mid

        // ================= Section 1 (pre-b_end) =================
        if (isG) {
            fr[0].hi = *(const bf16x8*)&sHGhi[c][q * 8];
            fr[1].hi = *(const bf16x8*)&sHGhi[c][32 + q * 8];
            fr[0].lo = *(const bf16x8*)&sHGlo[c][q * 8];
            fr[1].lo = *(const bf16x8*)&sHGlo[c][32 + q * 8];
        } else {
            fr[0].hi = *(const bf16x8*)&sHAhi[c][q * 8];
            fr[1].hi = *(const bf16x8*)&sHAhi[c][32 + q * 8];
            fr[0].lo = *(const bf16x8*)&sHAlo[c][q * 8];
            fr[1].lo = *(const bf16x8*)&sHAlo[c][32 + q * 8];
            aAR = mm3(fr[0], W[2], aAR); aAR = mm3(fr[1], W[3], aAR);
            aAZ = mm3(fr[0], W[6], aAZ); aAZ = mm3(fr[1], W[7], aAZ);
            #pragma unroll
            for (int i = 0; i < 4; i++) {
                float r = sigf(aAR[i]);
                z_c[i]  = sigf(aAZ[i]);
                float rh = r * hst[i];
                __bf16 hi = (__bf16)rh;
                int rr = q * 4 + i;
                sRHhi[rr][dglob] = hi;
                sRHlo[rr][dglob] = (__bf16)(rh - (float)hi);
            }
        }

        __syncthreads();  // b_end
    }

    // ---- epilogue: finalize ha(T-1) and write attn_vec (A group) ----
    if (!isG) {
        Frag rh0, rh1;
        rh0.hi = *(const bf16x8*)&sRHhi[c][q * 8];
        rh1.hi = *(const bf16x8*)&sRHhi[c][32 + q * 8];
        rh0.lo = *(const bf16x8*)&sRHlo[c][q * 8];
        rh1.lo = *(const bf16x8*)&sRHlo[c][32 + q * 8];
        aAH = mm3(rh0, W[10], aAH); aAH = mm3(rh1, W[11], aAH);
        #pragma unroll
        for (int i = 0; i < 4; i++) {
            int rr = q * 4 + i;
            const int p = (T_LEN - 1) & 1;
            float a = sigf(sParts[p][rr][0] + sParts[p][rr][1] +
                           sParts[p][rr][2] + sParts[p][rr][3]);
            float hh = tanh_fast(aAH[i]);
            float zz = a * z_c[i];
            float hv = (1.0f - zz) * hst[i] + zz * hh;
            out[NB + (row0 + rr) * 64 + dglob] = hv;
        }
    }

    // ---- aux_logits from hg(T-1) (G group) ----
    if (isG) {
        float pa[4];
        #pragma unroll
        for (int i = 0; i < 4; i++) pa[i] = hst[i] * auxwc;
        #pragma unroll
        for (int m = 1; m < 16; m <<= 1) {
            #pragma unroll
            for (int i = 0; i < 4; i++) pa[i] += __shfl_xor(pa[i], m, 64);
        }
        if (c == 0) {
            #pragma unroll
            for (int i = 0; i < 4; i++) sParts[0][q * 4 + i][wg] = pa[i];
        }
    }
    __syncthreads();
    if (tid < 16) {
        out[NB + NB * 64 + row0 + tid] =
            sParts[0][tid][0] + sParts[0][tid][1] + sParts[0][tid][2] + sParts[0][tid][3]
            + aux_b[0];
    }
}

extern "C" void kernel_launch(void* const* d_in, const int* in_sizes, int n_in,
                              void* d_out, int out_size, void* d_ws, size_t ws_size,
                              hipStream_t stream) {
    dien_fused<<<dim3(256), dim3(512), 0, stream>>>(
        (const int*)d_in[0],      // u_idx
        (const int*)d_in[1],      // i_idx
        (const int*)d_in[2],      // seq
        (const float*)d_in[3],    // item_emb
        (const float*)d_in[4],    // user_bias
        (const float*)d_in[5],    // item_bias
        (const float*)d_in[6],    // gru_w_ih
        (const float*)d_in[7],    // gru_b_ih
        (const float*)d_in[8],    // gru_w_hh
        (const float*)d_in[9],    // gru_b_hh
        (const float*)d_in[10],   // attn_w
        (const float*)d_in[11],   // attn_b
        (const float*)d_in[12],   // wr_w
        (const float*)d_in[13],   // wr_b
        (const float*)d_in[14],   // wz_w
        (const float*)d_in[15],   // wz_b
        (const float*)d_in[16],   // wh_w
        (const float*)d_in[17],   // wh_b
        (const float*)d_in[18],   // aux_w
        (const float*)d_in[19],   // aux_b
        (float*)d_out);
}

// Round 9
// 454.469 us; speedup vs baseline: 1.6489x; 1.1295x over previous
//
#include <hip/hip_runtime.h>

typedef __bf16 bf16x8 __attribute__((ext_vector_type(8)));
typedef float f32x4 __attribute__((ext_vector_type(4)));

#define T_LEN 200
#define NB 4096

__device__ __forceinline__ f32x4 mfma16(bf16x8 a, bf16x8 b, f32x4 c) {
    return __builtin_amdgcn_mfma_f32_16x16x32_bf16(a, b, c, 0, 0, 0);
}
__device__ __forceinline__ float sigf(float x) { return 1.0f / (1.0f + __expf(-x)); }
__device__ __forceinline__ float tanh_fast(float x) {
    x = fminf(15.0f, fmaxf(-15.0f, x));
    float e = __expf(2.0f * x);
    return (e - 1.0f) / (e + 1.0f);
}

// ---- trunc-based hi/lo split (hi = top 16 bits of fp32 == trunc-bf16) ----
__device__ __forceinline__ unsigned pack2(float a, float b) {  // [bf16(a), bf16(b)] packed
    return (__float_as_uint(a) >> 16) | (__float_as_uint(b) & 0xFFFF0000u);
}
__device__ __forceinline__ float lo_of(float v) {
    return v - __uint_as_float(__float_as_uint(v) & 0xFFFF0000u);
}
__device__ __forceinline__ void publish(unsigned short* hp, unsigned short* lp, float v) {
    unsigned b = __float_as_uint(v);
    *hp = (unsigned short)(b >> 16);
    float l = v - __uint_as_float(b & 0xFFFF0000u);
    *lp = (unsigned short)(__float_as_uint(l) >> 16);
}

// fp32-accurate fragment (hi/lo bf16 pair); RNE split for cold paths (weights/tp)
struct Frag { bf16x8 hi, lo; };
__device__ __forceinline__ Frag make_frag(f32x4 a, f32x4 b) {
    Frag f;
    #pragma unroll
    for (int j = 0; j < 4; j++) {
        float v = a[j]; __bf16 h = (__bf16)v;
        f.hi[j] = h; f.lo[j] = (__bf16)(v - (float)h);
    }
    #pragma unroll
    for (int j = 0; j < 4; j++) {
        float v = b[j]; __bf16 h = (__bf16)v;
        f.hi[4 + j] = h; f.lo[4 + j] = (__bf16)(v - (float)h);
    }
    return f;
}
__device__ __forceinline__ Frag load_split(const float* p) {
    return make_frag(*(const f32x4*)p, *(const f32x4*)(p + 4));
}
// acc += A*B, 3-term hi/lo product
__device__ __forceinline__ f32x4 mm3(Frag a, Frag b, f32x4 acc) {
    acc = mfma16(a.hi, b.hi, acc);
    acc = mfma16(a.hi, b.lo, acc);
    acc = mfma16(a.lo, b.hi, acc);
    return acc;
}

// 8 waves: 0-3 GRU (G), 4-7 AUGRU (A). AUGRU pipelined one step.
// LDS hazards (producer -> consumer crosses >=1 barrier):
//   sX  : W by G in S1(t) [x(t+1)], R by G+A in S0(t+1)   [b_end]
//   sHG : W by G in S0(t), R by G in S1(t)                 [b_mid]
//   sScore[p]: W by G(wg0) in S1(t) (p=t&1), R by A in S0(t+1) [b_end]
//   sHA : W by A in S0(t), R by A in S1(t)                 [b_mid]
//   sRH : W by A in S1(t), R by A in S0(t+1)/epilogue      [b_end]
__global__ __launch_bounds__(512, 2)
void dien_fused(const int* __restrict__ u_idx, const int* __restrict__ i_idx,
                const int* __restrict__ seq, const float* __restrict__ item_emb,
                const float* __restrict__ user_bias, const float* __restrict__ item_bias,
                const float* __restrict__ gw_ih, const float* __restrict__ gb_ih,
                const float* __restrict__ gw_hh, const float* __restrict__ gb_hh,
                const float* __restrict__ attn_w, const float* __restrict__ attn_b,
                const float* __restrict__ wr_w, const float* __restrict__ wr_b,
                const float* __restrict__ wz_w, const float* __restrict__ wz_b,
                const float* __restrict__ wh_w, const float* __restrict__ wh_b,
                const float* __restrict__ aux_w, const float* __restrict__ aux_b,
                float* __restrict__ out)
{
    __shared__ int sSeq[16][T_LEN];
    __shared__ __align__(16) float sTP[16][64];
    __shared__ __align__(16) unsigned short sHGhi[16][72], sHGlo[16][72];
    __shared__ __align__(16) unsigned short sHAhi[16][72], sHAlo[16][72];
    __shared__ __align__(16) unsigned short sRHhi[16][72], sRHlo[16][72];
    __shared__ __align__(16) unsigned short sXhi[16][72],  sXlo[16][72];
    __shared__ float sScore[2][16];
    __shared__ float sParts[16][4];

    const int tid  = threadIdx.x;
    const int wave = tid >> 6;           // 0..7
    const int lane = tid & 63;
    const int c    = lane & 15;
    const int q    = lane >> 4;
    const bool isG = (wave < 4);
    const int wg   = wave & 3;
    const int dglob = wg * 16 + c;
    const int row0 = blockIdx.x * 16;

    // ---- stage seq indices ----
    for (int i = tid; i < 16 * T_LEN; i += 512) {
        int b = i / T_LEN, t = i - b * T_LEN;
        sSeq[b][t] = seq[(row0 + b) * T_LEN + t];
    }

    // ---- fm1 ----
    if (tid < 16) {
        int b = row0 + tid;
        out[b] = user_bias[u_idx[b]] + item_bias[i_idx[b]];
    }

    // ---- target_proj (16x64 fp32), threads 0..255 ----
    if (tid < 256) {
        int b  = tid >> 4;
        int d0 = (tid & 15) * 4;
        const float* erow = item_emb + (long)i_idx[row0 + b] * 64;
        float e[64];
        #pragma unroll
        for (int k4 = 0; k4 < 16; k4++) {
            f32x4 v = *(const f32x4*)(erow + k4 * 4);
            #pragma unroll
            for (int j = 0; j < 4; j++) e[k4 * 4 + j] = v[j];
        }
        #pragma unroll
        for (int dd = 0; dd < 4; dd++) {
            int d = d0 + dd;
            const float* wrow = attn_w + d * 64;
            float s = attn_b[d];
            #pragma unroll
            for (int k4 = 0; k4 < 16; k4++) {
                f32x4 wv = *(const f32x4*)(wrow + k4 * 4);
                #pragma unroll
                for (int j = 0; j < 4; j++) s += e[k4 * 4 + j] * wv[j];
            }
            sTP[b][d] = s;
        }
    }

    // ---- zero ha exchange buffer; prime sX with x(0) (G waves) ----
    for (int i = tid; i < 16 * 72; i += 512) {
        sHAhi[0][i] = 0; sHAlo[0][i] = 0;
    }
    const int xrow = wg * 4 + (lane >> 4);   // producer row (G)
    const int xch  = lane & 15;              // 4-float chunk within row
    if (isG) {
        const float* p = item_emb + (long)seq[(row0 + xrow) * T_LEN + 0] * 64 + xch * 4;
        f32x4 v = *(const f32x4*)p;
        unsigned h01 = pack2(v[0], v[1]), h23 = pack2(v[2], v[3]);
        unsigned l01 = pack2(lo_of(v[0]), lo_of(v[1])), l23 = pack2(lo_of(v[2]), lo_of(v[3]));
        *(uint2*)&sXhi[xrow][xch * 4] = make_uint2(h01, h23);
        *(uint2*)&sXlo[xrow][xch * 4] = make_uint2(l01, l23);
    }
    __syncthreads();

    // ---- register-resident weights (hi/lo), unioned across groups ----
    // G: W[0..1]=wih_r, W[2..3]=wih_z, W[4..5]=wih_n, W[6..7]=whh_r, W[8..9]=whh_z, W[10..11]=whh_n
    // A: W[0..1]=wrx, W[2..3]=wrh, W[4..5]=wzx, W[6..7]=wzh, W[8..9]=whx, W[10..11]=whhat
    Frag W[12];
    if (isG) {
        #pragma unroll
        for (int g = 0; g < 3; g++)
            #pragma unroll
            for (int s = 0; s < 2; s++) {
                W[g * 2 + s]     = load_split(gw_ih + (g * 64 + dglob) * 64 + s * 32 + q * 8);
                W[6 + g * 2 + s] = load_split(gw_hh + (g * 64 + dglob) * 64 + s * 32 + q * 8);
            }
    } else {
        #pragma unroll
        for (int s = 0; s < 2; s++) {
            const int fo = dglob * 128 + s * 32 + q * 8;
            W[0 + s]  = load_split(wr_w + fo);
            W[2 + s]  = load_split(wr_w + fo + 64);
            W[4 + s]  = load_split(wz_w + fo);
            W[6 + s]  = load_split(wz_w + fo + 64);
            W[8 + s]  = load_split(wh_w + fo);
            W[10 + s] = load_split(wh_w + fo + 64);
        }
    }

    float bA, bB, bC, bD;
    if (isG) {
        bA = gb_ih[dglob] + gb_hh[dglob];
        bB = gb_ih[64 + dglob] + gb_hh[64 + dglob];
        bC = gb_ih[128 + dglob];
        bD = gb_hh[128 + dglob];
    } else {
        bA = wr_b[dglob];
        bB = wz_b[dglob];
        bC = wh_b[dglob];
        bD = 0.0f;
    }
    const float auxwc = aux_w[dglob];

    // TP as B-fragment (G only): B[k][n] = tp[n=c][k = s*32 + q*8 + j]
    Frag tpB0, tpB1;
    if (isG) {
        tpB0 = make_frag(*(const f32x4*)&sTP[c][q * 8], *(const f32x4*)&sTP[c][q * 8 + 4]);
        tpB1 = make_frag(*(const f32x4*)&sTP[c][32 + q * 8], *(const f32x4*)&sTP[c][32 + q * 8 + 4]);
    }

    // ---- state ----
    float hst[4] = {0.f, 0.f, 0.f, 0.f};   // G: hg(t); A: ha(t-1)
    Frag fr[2];                             // G: hg frags; A: ha frags
    #pragma unroll
    for (int s = 0; s < 2; s++)
        #pragma unroll
        for (int j = 0; j < 8; j++) { fr[s].hi[j] = (__bf16)0.f; fr[s].lo[j] = (__bf16)0.f; }
    f32x4 aAH = {0.f, 0.f, 0.f, 0.f};
    float z_c[4] = {0.f, 0.f, 0.f, 0.f};

    for (int t = 0; t < T_LEN; t++) {
        f32x4 xg;         // G: x(t+1) raw (global), consumed in S1
        f32x4 aAR, aAZ;   // A: r/z preactivations, live S0 -> S1

        // ================= Section 0 =================
        // both groups: x(t) frags from LDS (staged S1(t-1))
        Frag xA0, xA1;
        xA0.hi = *(const bf16x8*)&sXhi[c][q * 8];
        xA1.hi = *(const bf16x8*)&sXhi[c][32 + q * 8];
        xA0.lo = *(const bf16x8*)&sXlo[c][q * 8];
        xA1.lo = *(const bf16x8*)&sXlo[c][32 + q * 8];

        if (isG) {
            // issue global load of x(t+1) early (consumed in S1)
            int tn = (t + 1 < T_LEN) ? t + 1 : t;
            xg = *(const f32x4*)(item_emb + (long)sSeq[xrow][tn] * 64 + xch * 4);

            f32x4 accR = {bA, bA, bA, bA};
            accR = mm3(xA0, W[0], accR); accR = mm3(xA1, W[1], accR);
            accR = mm3(fr[0], W[6], accR); accR = mm3(fr[1], W[7], accR);
            f32x4 accZ = {bB, bB, bB, bB};
            accZ = mm3(xA0, W[2], accZ); accZ = mm3(xA1, W[3], accZ);
            accZ = mm3(fr[0], W[8], accZ); accZ = mm3(fr[1], W[9], accZ);
            f32x4 accNX = {bC, bC, bC, bC};
            accNX = mm3(xA0, W[4], accNX); accNX = mm3(xA1, W[5], accNX);
            f32x4 accNH = {bD, bD, bD, bD};
            accNH = mm3(fr[0], W[10], accNH); accNH = mm3(fr[1], W[11], accNH);

            #pragma unroll
            for (int i = 0; i < 4; i++) {
                float r = sigf(accR[i]);
                float z = sigf(accZ[i]);
                float n = tanh_fast(accNX[i] + r * accNH[i]);
                float hn = (1.0f - z) * n + z * hst[i];
                hst[i] = hn;
                int rr = q * 4 + i;
                publish(&sHGhi[rr][dglob], &sHGlo[rr][dglob], hn);
            }
        } else {
            if (t > 0) {
                Frag rh0, rh1;
                rh0.hi = *(const bf16x8*)&sRHhi[c][q * 8];
                rh1.hi = *(const bf16x8*)&sRHhi[c][32 + q * 8];
                rh0.lo = *(const bf16x8*)&sRHlo[c][q * 8];
                rh1.lo = *(const bf16x8*)&sRHlo[c][32 + q * 8];
                aAH = mm3(rh0, W[10], aAH); aAH = mm3(rh1, W[11], aAH);
                #pragma unroll
                for (int i = 0; i < 4; i++) {
                    int rr = q * 4 + i;
                    float a = sigf(sScore[(t - 1) & 1][rr]);
                    float hh = tanh_fast(aAH[i]);
                    float zz = a * z_c[i];
                    float hv = (1.0f - zz) * hst[i] + zz * hh;
                    hst[i] = hv;
                    publish(&sHAhi[rr][dglob], &sHAlo[rr][dglob], hv);
                }
            }
            aAR = (f32x4){bA, bA, bA, bA};
            aAR = mm3(xA0, W[0], aAR); aAR = mm3(xA1, W[1], aAR);
            aAZ = (f32x4){bB, bB, bB, bB};
            aAZ = mm3(xA0, W[4], aAZ); aAZ = mm3(xA1, W[5], aAZ);
            aAH = (f32x4){bC, bC, bC, bC};
            aAH = mm3(xA0, W[8], aAH); aAH = mm3(xA1, W[9], aAH);
        }

        __syncthreads();  // b_mid

        // ================= Section 1 =================
        if (isG) {
            fr[0].hi = *(const bf16x8*)&sHGhi[c][q * 8];
            fr[1].hi = *(const bf16x8*)&sHGhi[c][32 + q * 8];
            fr[0].lo = *(const bf16x8*)&sHGlo[c][q * 8];
            fr[1].lo = *(const bf16x8*)&sHGlo[c][32 + q * 8];
            // score(t) = diag(hg(t) . tp^T) via MFMA
            f32x4 sc = {0.f, 0.f, 0.f, 0.f};
            sc = mm3(fr[0], tpB0, sc);
            sc = mm3(fr[1], tpB1, sc);
            if (wg == 0 && (c >> 2) == q) {
                int i = c & 3;
                float d = (i == 0) ? sc[0] : (i == 1) ? sc[1] : (i == 2) ? sc[2] : sc[3];
                sScore[t & 1][c] = d;
            }
            // stage x(t+1) pre-split into sX
            unsigned h01 = pack2(xg[0], xg[1]), h23 = pack2(xg[2], xg[3]);
            unsigned l01 = pack2(lo_of(xg[0]), lo_of(xg[1]));
            unsigned l23 = pack2(lo_of(xg[2]), lo_of(xg[3]));
            *(uint2*)&sXhi[xrow][xch * 4] = make_uint2(h01, h23);
            *(uint2*)&sXlo[xrow][xch * 4] = make_uint2(l01, l23);
        } else {
            fr[0].hi = *(const bf16x8*)&sHAhi[c][q * 8];
            fr[1].hi = *(const bf16x8*)&sHAhi[c][32 + q * 8];
            fr[0].lo = *(const bf16x8*)&sHAlo[c][q * 8];
            fr[1].lo = *(const bf16x8*)&sHAlo[c][32 + q * 8];
            aAR = mm3(fr[0], W[2], aAR); aAR = mm3(fr[1], W[3], aAR);
            aAZ = mm3(fr[0], W[6], aAZ); aAZ = mm3(fr[1], W[7], aAZ);
            #pragma unroll
            for (int i = 0; i < 4; i++) {
                float r = sigf(aAR[i]);
                z_c[i]  = sigf(aAZ[i]);
                float rh = r * hst[i];
                int rr = q * 4 + i;
                publish(&sRHhi[rr][dglob], &sRHlo[rr][dglob], rh);
            }
        }

        __syncthreads();  // b_end
    }

    // ---- epilogue: A finalizes ha(T-1), writes attn_vec ----
    if (!isG) {
        Frag rh0, rh1;
        rh0.hi = *(const bf16x8*)&sRHhi[c][q * 8];
        rh1.hi = *(const bf16x8*)&sRHhi[c][32 + q * 8];
        rh0.lo = *(const bf16x8*)&sRHlo[c][q * 8];
        rh1.lo = *(const bf16x8*)&sRHlo[c][32 + q * 8];
        aAH = mm3(rh0, W[10], aAH); aAH = mm3(rh1, W[11], aAH);
        #pragma unroll
        for (int i = 0; i < 4; i++) {
            int rr = q * 4 + i;
            float a = sigf(sScore[(T_LEN - 1) & 1][rr]);
            float hh = tanh_fast(aAH[i]);
            float zz = a * z_c[i];
            float hv = (1.0f - zz) * hst[i] + zz * hh;
            out[NB + (row0 + rr) * 64 + dglob] = hv;
        }
    }

    // ---- aux_logits from hg(T-1) (G group) ----
    if (isG) {
        float pa[4];
        #pragma unroll
        for (int i = 0; i < 4; i++) pa[i] = hst[i] * auxwc;
        #pragma unroll
        for (int m = 1; m < 16; m <<= 1) {
            #pragma unroll
            for (int i = 0; i < 4; i++) pa[i] += __shfl_xor(pa[i], m, 64);
        }
        if (c == 0) {
            #pragma unroll
            for (int i = 0; i < 4; i++) sParts[q * 4 + i][wg] = pa[i];
        }
    }
    __syncthreads();
    if (tid < 16) {
        out[NB + NB * 64 + row0 + tid] =
            sParts[tid][0] + sParts[tid][1] + sParts[tid][2] + sParts[tid][3] + aux_b[0];
    }
}

extern "C" void kernel_launch(void* const* d_in, const int* in_sizes, int n_in,
                              void* d_out, int out_size, void* d_ws, size_t ws_size,
                              hipStream_t stream) {
    dien_fused<<<dim3(256), dim3(512), 0, stream>>>(
        (const int*)d_in[0],      // u_idx
        (const int*)d_in[1],      // i_idx
        (const int*)d_in[2],      // seq
        (const float*)d_in[3],    // item_emb
        (const float*)d_in[4],    // user_bias
        (const float*)d_in[5],    // item_bias
        (const float*)d_in[6],    // gru_w_ih
        (const float*)d_in[7],    // gru_b_ih
        (const float*)d_in[8],    // gru_w_hh
        (const float*)d_in[9],    // gru_b_hh
        (const float*)d_in[10],   // attn_w
        (const float*)d_in[11],   // attn_b
        (const float*)d_in[12],   // wr_w
        (const float*)d_in[13],   // wr_b
        (const float*)d_in[14],   // wz_w
        (const float*)d_in[15],   // wz_b
        (const float*)d_in[16],   // wh_w
        (const float*)d_in[17],   // wh_b
        (const float*)d_in[18],   // aux_w
        (const float*)d_in[19],   // aux_b
        (float*)d_out);
}

// Round 10
// 433.417 us; speedup vs baseline: 1.7290x; 1.0486x over previous
//
#include <hip/hip_runtime.h>

typedef __bf16 bf16x8 __attribute__((ext_vector_type(8)));
typedef float f32x4 __attribute__((ext_vector_type(4)));

#define T_LEN 200
#define NB 4096

__device__ __forceinline__ f32x4 mfma16(bf16x8 a, bf16x8 b, f32x4 c) {
    return __builtin_amdgcn_mfma_f32_16x16x32_bf16(a, b, c, 0, 0, 0);
}
// sigmoid: 1/(1+exp(-x)); tanh: 1 - 2/(exp(2x)+1)  (clamp-free, inf-safe)
__device__ __forceinline__ float sigf(float x) { return 1.0f / (1.0f + __expf(-x)); }
__device__ __forceinline__ float tanh_fast(float x) {
    return 1.0f - 2.0f / (__expf(2.0f * x) + 1.0f);
}

// ---- x staging split (trunc-based; lo captures remainder, error ~2^-16) ----
__device__ __forceinline__ unsigned pack2(float a, float b) {
    return (__float_as_uint(a) >> 16) | (__float_as_uint(b) & 0xFFFF0000u);
}
__device__ __forceinline__ float lo_of(float v) {
    return v - __uint_as_float(__float_as_uint(v) & 0xFFFF0000u);
}
// ---- RNE publish (v_cvt pk bf16 is cheap; halves split error vs trunc) ----
__device__ __forceinline__ void publish(unsigned short* hp, unsigned short* lp, float v) {
    __bf16 h = (__bf16)v;                      // RNE
    *hp = __builtin_bit_cast(unsigned short, h);
    __bf16 l = (__bf16)(v - (float)h);
    *lp = __builtin_bit_cast(unsigned short, l);
}

// fp32-accurate A-side fragment (hi/lo bf16 pair)
struct Frag { bf16x8 hi, lo; };
__device__ __forceinline__ Frag make_frag(f32x4 a, f32x4 b) {
    Frag f;
    #pragma unroll
    for (int j = 0; j < 4; j++) {
        float v = a[j]; __bf16 h = (__bf16)v;
        f.hi[j] = h; f.lo[j] = (__bf16)(v - (float)h);
    }
    #pragma unroll
    for (int j = 0; j < 4; j++) {
        float v = b[j]; __bf16 h = (__bf16)v;
        f.hi[4 + j] = h; f.lo[4 + j] = (__bf16)(v - (float)h);
    }
    return f;
}
__device__ __forceinline__ bf16x8 load_w(const float* p) {   // W: bf16-hi (RNE) only
    f32x4 a = *(const f32x4*)p, b = *(const f32x4*)(p + 4);
    bf16x8 w;
    #pragma unroll
    for (int j = 0; j < 4; j++) { w[j] = (__bf16)a[j]; w[4 + j] = (__bf16)b[j]; }
    return w;
}
// acc += (A.hi + A.lo) * W
__device__ __forceinline__ f32x4 mm2(Frag a, bf16x8 w, f32x4 acc) {
    acc = mfma16(a.hi, w, acc);
    acc = mfma16(a.lo, w, acc);
    return acc;
}
// full 3-term product (kept for the score path: tp stays hi/lo)
__device__ __forceinline__ f32x4 mm3(Frag a, Frag b, f32x4 acc) {
    acc = mfma16(a.hi, b.hi, acc);
    acc = mfma16(a.hi, b.lo, acc);
    acc = mfma16(a.lo, b.hi, acc);
    return acc;
}

// 8 waves: 0-3 GRU (G), 4-7 AUGRU (A). AUGRU pipelined one step.
// LDS hazards (producer -> consumer crosses >=1 barrier):
//   sX  : W by G in S1(t) [x(t+1)], R by G+A in S0(t+1)   [b_end]
//   sHG : W by G in S0(t), R by G in S1(t)                 [b_mid]
//   sScore[p]: W by G(wg0) in S1(t) (p=t&1), R by A in S0(t+1) [b_end]
//   sHA : W by A in S0(t), R by A in S1(t)                 [b_mid]
//   sRH : W by A in S1(t), R by A in S0(t+1)/epilogue      [b_end]
__global__ __launch_bounds__(512, 2)
void dien_fused(const int* __restrict__ u_idx, const int* __restrict__ i_idx,
                const int* __restrict__ seq, const float* __restrict__ item_emb,
                const float* __restrict__ user_bias, const float* __restrict__ item_bias,
                const float* __restrict__ gw_ih, const float* __restrict__ gb_ih,
                const float* __restrict__ gw_hh, const float* __restrict__ gb_hh,
                const float* __restrict__ attn_w, const float* __restrict__ attn_b,
                const float* __restrict__ wr_w, const float* __restrict__ wr_b,
                const float* __restrict__ wz_w, const float* __restrict__ wz_b,
                const float* __restrict__ wh_w, const float* __restrict__ wh_b,
                const float* __restrict__ aux_w, const float* __restrict__ aux_b,
                float* __restrict__ out)
{
    __shared__ int sSeq[16][T_LEN];
    __shared__ __align__(16) float sTP[16][64];
    __shared__ __align__(16) unsigned short sHGhi[16][72], sHGlo[16][72];
    __shared__ __align__(16) unsigned short sHAhi[16][72], sHAlo[16][72];
    __shared__ __align__(16) unsigned short sRHhi[16][72], sRHlo[16][72];
    __shared__ __align__(16) unsigned short sXhi[16][72],  sXlo[16][72];
    __shared__ float sScore[2][16];
    __shared__ float sParts[16][4];

    const int tid  = threadIdx.x;
    const int wave = tid >> 6;           // 0..7
    const int lane = tid & 63;
    const int c    = lane & 15;
    const int q    = lane >> 4;
    const bool isG = (wave < 4);
    const int wg   = wave & 3;
    const int dglob = wg * 16 + c;
    const int row0 = blockIdx.x * 16;

    // ---- stage seq indices ----
    for (int i = tid; i < 16 * T_LEN; i += 512) {
        int b = i / T_LEN, t = i - b * T_LEN;
        sSeq[b][t] = seq[(row0 + b) * T_LEN + t];
    }

    // ---- fm1 ----
    if (tid < 16) {
        int b = row0 + tid;
        out[b] = user_bias[u_idx[b]] + item_bias[i_idx[b]];
    }

    // ---- target_proj (16x64 fp32), threads 0..255 ----
    if (tid < 256) {
        int b  = tid >> 4;
        int d0 = (tid & 15) * 4;
        const float* erow = item_emb + (long)i_idx[row0 + b] * 64;
        float e[64];
        #pragma unroll
        for (int k4 = 0; k4 < 16; k4++) {
            f32x4 v = *(const f32x4*)(erow + k4 * 4);
            #pragma unroll
            for (int j = 0; j < 4; j++) e[k4 * 4 + j] = v[j];
        }
        #pragma unroll
        for (int dd = 0; dd < 4; dd++) {
            int d = d0 + dd;
            const float* wrow = attn_w + d * 64;
            float s = attn_b[d];
            #pragma unroll
            for (int k4 = 0; k4 < 16; k4++) {
                f32x4 wv = *(const f32x4*)(wrow + k4 * 4);
                #pragma unroll
                for (int j = 0; j < 4; j++) s += e[k4 * 4 + j] * wv[j];
            }
            sTP[b][d] = s;
        }
    }

    // ---- zero ha exchange buffer; prime sX with x(0) (G waves) ----
    for (int i = tid; i < 16 * 72; i += 512) {
        sHAhi[0][i] = 0; sHAlo[0][i] = 0;
    }
    const int xrow = wg * 4 + (lane >> 4);   // producer row (G)
    const int xch  = lane & 15;              // 4-float chunk within row
    if (isG) {
        const float* p = item_emb + (long)seq[(row0 + xrow) * T_LEN + 0] * 64 + xch * 4;
        f32x4 v = *(const f32x4*)p;
        unsigned h01 = pack2(v[0], v[1]), h23 = pack2(v[2], v[3]);
        unsigned l01 = pack2(lo_of(v[0]), lo_of(v[1])), l23 = pack2(lo_of(v[2]), lo_of(v[3]));
        *(uint2*)&sXhi[xrow][xch * 4] = make_uint2(h01, h23);
        *(uint2*)&sXlo[xrow][xch * 4] = make_uint2(l01, l23);
    }
    __syncthreads();

    // ---- register-resident weights (bf16-hi RNE), unioned across groups ----
    // G: W[0..1]=wih_r, W[2..3]=wih_z, W[4..5]=wih_n, W[6..7]=whh_r, W[8..9]=whh_z, W[10..11]=whh_n
    // A: W[0..1]=wrx, W[2..3]=wrh, W[4..5]=wzx, W[6..7]=wzh, W[8..9]=whx, W[10..11]=whhat
    bf16x8 W[12];
    if (isG) {
        #pragma unroll
        for (int g = 0; g < 3; g++)
            #pragma unroll
            for (int s = 0; s < 2; s++) {
                W[g * 2 + s]     = load_w(gw_ih + (g * 64 + dglob) * 64 + s * 32 + q * 8);
                W[6 + g * 2 + s] = load_w(gw_hh + (g * 64 + dglob) * 64 + s * 32 + q * 8);
            }
    } else {
        #pragma unroll
        for (int s = 0; s < 2; s++) {
            const int fo = dglob * 128 + s * 32 + q * 8;
            W[0 + s]  = load_w(wr_w + fo);
            W[2 + s]  = load_w(wr_w + fo + 64);
            W[4 + s]  = load_w(wz_w + fo);
            W[6 + s]  = load_w(wz_w + fo + 64);
            W[8 + s]  = load_w(wh_w + fo);
            W[10 + s] = load_w(wh_w + fo + 64);
        }
    }

    float bA, bB, bC, bD;
    if (isG) {
        bA = gb_ih[dglob] + gb_hh[dglob];
        bB = gb_ih[64 + dglob] + gb_hh[64 + dglob];
        bC = gb_ih[128 + dglob];
        bD = gb_hh[128 + dglob];
    } else {
        bA = wr_b[dglob];
        bB = wz_b[dglob];
        bC = wh_b[dglob];
        bD = 0.0f;
    }
    const float auxwc = aux_w[dglob];

    // TP as B-fragment (G only), kept hi/lo (score feeds sigmoid; keep accurate)
    Frag tpB0, tpB1;
    if (isG) {
        tpB0 = make_frag(*(const f32x4*)&sTP[c][q * 8], *(const f32x4*)&sTP[c][q * 8 + 4]);
        tpB1 = make_frag(*(const f32x4*)&sTP[c][32 + q * 8], *(const f32x4*)&sTP[c][32 + q * 8 + 4]);
    }

    // ---- state ----
    float hst[4] = {0.f, 0.f, 0.f, 0.f};   // G: hg(t); A: ha(t-1)
    Frag fr[2];                             // G: hg frags; A: ha frags
    #pragma unroll
    for (int s = 0; s < 2; s++)
        #pragma unroll
        for (int j = 0; j < 8; j++) { fr[s].hi[j] = (__bf16)0.f; fr[s].lo[j] = (__bf16)0.f; }
    f32x4 aAH = {0.f, 0.f, 0.f, 0.f};
    float z_c[4] = {0.f, 0.f, 0.f, 0.f};

    for (int t = 0; t < T_LEN; t++) {
        f32x4 xg;         // G: x(t+1) raw (global), consumed in S1
        f32x4 aAR, aAZ;   // A: r/z preactivations, live S0 -> S1

        // ================= Section 0 =================
        Frag xA0, xA1;
        xA0.hi = *(const bf16x8*)&sXhi[c][q * 8];
        xA1.hi = *(const bf16x8*)&sXhi[c][32 + q * 8];
        xA0.lo = *(const bf16x8*)&sXlo[c][q * 8];
        xA1.lo = *(const bf16x8*)&sXlo[c][32 + q * 8];

        if (isG) {
            int tn = (t + 1 < T_LEN) ? t + 1 : t;
            xg = *(const f32x4*)(item_emb + (long)sSeq[xrow][tn] * 64 + xch * 4);

            f32x4 accR = {bA, bA, bA, bA};
            accR = mm2(xA0, W[0], accR); accR = mm2(xA1, W[1], accR);
            accR = mm2(fr[0], W[6], accR); accR = mm2(fr[1], W[7], accR);
            f32x4 accZ = {bB, bB, bB, bB};
            accZ = mm2(xA0, W[2], accZ); accZ = mm2(xA1, W[3], accZ);
            accZ = mm2(fr[0], W[8], accZ); accZ = mm2(fr[1], W[9], accZ);
            f32x4 accNX = {bC, bC, bC, bC};
            accNX = mm2(xA0, W[4], accNX); accNX = mm2(xA1, W[5], accNX);
            f32x4 accNH = {bD, bD, bD, bD};
            accNH = mm2(fr[0], W[10], accNH); accNH = mm2(fr[1], W[11], accNH);

            #pragma unroll
            for (int i = 0; i < 4; i++) {
                float r = sigf(accR[i]);
                float z = sigf(accZ[i]);
                float n = tanh_fast(accNX[i] + r * accNH[i]);
                float hn = n + z * (hst[i] - n);
                hst[i] = hn;
                int rr = q * 4 + i;
                publish(&sHGhi[rr][dglob], &sHGlo[rr][dglob], hn);
            }
        } else {
            if (t > 0) {
                Frag rh0, rh1;
                rh0.hi = *(const bf16x8*)&sRHhi[c][q * 8];
                rh1.hi = *(const bf16x8*)&sRHhi[c][32 + q * 8];
                rh0.lo = *(const bf16x8*)&sRHlo[c][q * 8];
                rh1.lo = *(const bf16x8*)&sRHlo[c][32 + q * 8];
                aAH = mm2(rh0, W[10], aAH); aAH = mm2(rh1, W[11], aAH);
                #pragma unroll
                for (int i = 0; i < 4; i++) {
                    int rr = q * 4 + i;
                    float a = sigf(sScore[(t - 1) & 1][rr]);
                    float hh = tanh_fast(aAH[i]);
                    float zz = a * z_c[i];
                    float hv = hst[i] + zz * (hh - hst[i]);
                    hst[i] = hv;
                    publish(&sHAhi[rr][dglob], &sHAlo[rr][dglob], hv);
                }
            }
            aAR = (f32x4){bA, bA, bA, bA};
            aAR = mm2(xA0, W[0], aAR); aAR = mm2(xA1, W[1], aAR);
            aAZ = (f32x4){bB, bB, bB, bB};
            aAZ = mm2(xA0, W[4], aAZ); aAZ = mm2(xA1, W[5], aAZ);
            aAH = (f32x4){bC, bC, bC, bC};
            aAH = mm2(xA0, W[8], aAH); aAH = mm2(xA1, W[9], aAH);
        }

        __syncthreads();  // b_mid

        // ================= Section 1 =================
        if (isG) {
            fr[0].hi = *(const bf16x8*)&sHGhi[c][q * 8];
            fr[1].hi = *(const bf16x8*)&sHGhi[c][32 + q * 8];
            fr[0].lo = *(const bf16x8*)&sHGlo[c][q * 8];
            fr[1].lo = *(const bf16x8*)&sHGlo[c][32 + q * 8];
            // score(t) = diag(hg(t) . tp^T) via MFMA
            f32x4 sc = {0.f, 0.f, 0.f, 0.f};
            sc = mm3(fr[0], tpB0, sc);
            sc = mm3(fr[1], tpB1, sc);
            if (wg == 0 && (c >> 2) == q) {
                int i = c & 3;
                float d = (i == 0) ? sc[0] : (i == 1) ? sc[1] : (i == 2) ? sc[2] : sc[3];
                sScore[t & 1][c] = d;
            }
            // stage x(t+1) pre-split into sX
            unsigned h01 = pack2(xg[0], xg[1]), h23 = pack2(xg[2], xg[3]);
            unsigned l01 = pack2(lo_of(xg[0]), lo_of(xg[1]));
            unsigned l23 = pack2(lo_of(xg[2]), lo_of(xg[3]));
            *(uint2*)&sXhi[xrow][xch * 4] = make_uint2(h01, h23);
            *(uint2*)&sXlo[xrow][xch * 4] = make_uint2(l01, l23);
        } else {
            fr[0].hi = *(const bf16x8*)&sHAhi[c][q * 8];
            fr[1].hi = *(const bf16x8*)&sHAhi[c][32 + q * 8];
            fr[0].lo = *(const bf16x8*)&sHAlo[c][q * 8];
            fr[1].lo = *(const bf16x8*)&sHAlo[c][32 + q * 8];
            aAR = mm2(fr[0], W[2], aAR); aAR = mm2(fr[1], W[3], aAR);
            aAZ = mm2(fr[0], W[6], aAZ); aAZ = mm2(fr[1], W[7], aAZ);
            #pragma unroll
            for (int i = 0; i < 4; i++) {
                float r = sigf(aAR[i]);
                z_c[i]  = sigf(aAZ[i]);
                float rh = r * hst[i];
                int rr = q * 4 + i;
                publish(&sRHhi[rr][dglob], &sRHlo[rr][dglob], rh);
            }
        }

        __syncthreads();  // b_end
    }

    // ---- epilogue: A finalizes ha(T-1), writes attn_vec ----
    if (!isG) {
        Frag rh0, rh1;
        rh0.hi = *(const bf16x8*)&sRHhi[c][q * 8];
        rh1.hi = *(const bf16x8*)&sRHhi[c][32 + q * 8];
        rh0.lo = *(const bf16x8*)&sRHlo[c][q * 8];
        rh1.lo = *(const bf16x8*)&sRHlo[c][32 + q * 8];
        aAH = mm2(rh0, W[10], aAH); aAH = mm2(rh1, W[11], aAH);
        #pragma unroll
        for (int i = 0; i < 4; i++) {
            int rr = q * 4 + i;
            float a = sigf(sScore[(T_LEN - 1) & 1][rr]);
            float hh = tanh_fast(aAH[i]);
            float zz = a * z_c[i];
            float hv = hst[i] + zz * (hh - hst[i]);
            out[NB + (row0 + rr) * 64 + dglob] = hv;
        }
    }

    // ---- aux_logits from hg(T-1) (G group) ----
    if (isG) {
        float pa[4];
        #pragma unroll
        for (int i = 0; i < 4; i++) pa[i] = hst[i] * auxwc;
        #pragma unroll
        for (int m = 1; m < 16; m <<= 1) {
            #pragma unroll
            for (int i = 0; i < 4; i++) pa[i] += __shfl_xor(pa[i], m, 64);
        }
        if (c == 0) {
            #pragma unroll
            for (int i = 0; i < 4; i++) sParts[q * 4 + i][wg] = pa[i];
        }
    }
    __syncthreads();
    if (tid < 16) {
        out[NB + NB * 64 + row0 + tid] =
            sParts[tid][0] + sParts[tid][1] + sParts[tid][2] + sParts[tid][3] + aux_b[0];
    }
}

extern "C" void kernel_launch(void* const* d_in, const int* in_sizes, int n_in,
                              void* d_out, int out_size, void* d_ws, size_t ws_size,
                              hipStream_t stream) {
    dien_fused<<<dim3(256), dim3(512), 0, stream>>>(
        (const int*)d_in[0],      // u_idx
        (const int*)d_in[1],      // i_idx
        (const int*)d_in[2],      // seq
        (const float*)d_in[3],    // item_emb
        (const float*)d_in[4],    // user_bias
        (const float*)d_in[5],    // item_bias
        (const float*)d_in[6],    // gru_w_ih
        (const float*)d_in[7],    // gru_b_ih
        (const float*)d_in[8],    // gru_w_hh
        (const float*)d_in[9],    // gru_b_hh
        (const float*)d_in[10],   // attn_w
        (const float*)d_in[11],   // attn_b
        (const float*)d_in[12],   // wr_w
        (const float*)d_in[13],   // wr_b
        (const float*)d_in[14],   // wz_w
        (const float*)d_in[15],   // wz_b
        (const float*)d_in[16],   // wh_w
        (const float*)d_in[17],   // wh_b
        (const float*)d_in[18],   // aux_w
        (const float*)d_in[19],   // aux_b
        (float*)d_out);
}

// Round 11
// 331.734 us; speedup vs baseline: 2.2590x; 1.3065x over previous
//
#include <hip/hip_runtime.h>

typedef __bf16 bf16x8 __attribute__((ext_vector_type(8)));
typedef float f32x4 __attribute__((ext_vector_type(4)));

#define T_LEN 200
#define NB 4096

__device__ __forceinline__ f32x4 mfma16(bf16x8 a, bf16x8 b, f32x4 c) {
    return __builtin_amdgcn_mfma_f32_16x16x32_bf16(a, b, c, 0, 0, 0);
}
// Fast transcendentals: raw v_rcp_f32 (1 ulp) instead of IEEE divide sequence.
// sigf: rcp(inf)=0, rcp(1)=1 -> saturation exact, no clamps needed.
__device__ __forceinline__ float sigf(float x) {
    return __builtin_amdgcn_rcpf(1.0f + __expf(-x));
}
__device__ __forceinline__ float tanh_fast(float x) {
    return 1.0f - 2.0f * __builtin_amdgcn_rcpf(__expf(2.0f * x) + 1.0f);
}

// ---- x staging split (trunc-based; lo captures remainder, error ~2^-16) ----
__device__ __forceinline__ unsigned pack2(float a, float b) {
    return (__float_as_uint(a) >> 16) | (__float_as_uint(b) & 0xFFFF0000u);
}
__device__ __forceinline__ float lo_of(float v) {
    return v - __uint_as_float(__float_as_uint(v) & 0xFFFF0000u);
}
// ---- RNE publish ----
__device__ __forceinline__ void publish(unsigned short* hp, unsigned short* lp, float v) {
    __bf16 h = (__bf16)v;                      // RNE
    *hp = __builtin_bit_cast(unsigned short, h);
    __bf16 l = (__bf16)(v - (float)h);
    *lp = __builtin_bit_cast(unsigned short, l);
}

// fp32-accurate A-side fragment (hi/lo bf16 pair)
struct Frag { bf16x8 hi, lo; };
__device__ __forceinline__ Frag make_frag(f32x4 a, f32x4 b) {
    Frag f;
    #pragma unroll
    for (int j = 0; j < 4; j++) {
        float v = a[j]; __bf16 h = (__bf16)v;
        f.hi[j] = h; f.lo[j] = (__bf16)(v - (float)h);
    }
    #pragma unroll
    for (int j = 0; j < 4; j++) {
        float v = b[j]; __bf16 h = (__bf16)v;
        f.hi[4 + j] = h; f.lo[4 + j] = (__bf16)(v - (float)h);
    }
    return f;
}
__device__ __forceinline__ bf16x8 load_w(const float* p) {   // W: bf16-hi (RNE) only
    f32x4 a = *(const f32x4*)p, b = *(const f32x4*)(p + 4);
    bf16x8 w;
    #pragma unroll
    for (int j = 0; j < 4; j++) { w[j] = (__bf16)a[j]; w[4 + j] = (__bf16)b[j]; }
    return w;
}
// acc += (A.hi + A.lo) * W
__device__ __forceinline__ f32x4 mm2(Frag a, bf16x8 w, f32x4 acc) {
    acc = mfma16(a.hi, w, acc);
    acc = mfma16(a.lo, w, acc);
    return acc;
}
// full 3-term product (score path: tp stays hi/lo)
__device__ __forceinline__ f32x4 mm3(Frag a, Frag b, f32x4 acc) {
    acc = mfma16(a.hi, b.hi, acc);
    acc = mfma16(a.hi, b.lo, acc);
    acc = mfma16(a.lo, b.hi, acc);
    return acc;
}

// 8 waves: 0-3 GRU (G), 4-7 AUGRU (A). AUGRU pipelined one step.
// LDS hazards (producer -> consumer crosses >=1 barrier):
//   sX  : W by G in S1(t) [x(t+1)], R by G+A in S0(t+1)   [b_end]
//   sHG : W by G in S0(t), R by G in S1(t)                 [b_mid]
//   sScore[p]: W by G(wg0) in S1(t) (p=t&1), R by A in S0(t+1) [b_end]
//   sHA : W by A in S0(t), R by A in S1(t)                 [b_mid]
//   sRH : W by A in S1(t), R by A in S0(t+1)/epilogue      [b_end]
__global__ __launch_bounds__(512, 2)
void dien_fused(const int* __restrict__ u_idx, const int* __restrict__ i_idx,
                const int* __restrict__ seq, const float* __restrict__ item_emb,
                const float* __restrict__ user_bias, const float* __restrict__ item_bias,
                const float* __restrict__ gw_ih, const float* __restrict__ gb_ih,
                const float* __restrict__ gw_hh, const float* __restrict__ gb_hh,
                const float* __restrict__ attn_w, const float* __restrict__ attn_b,
                const float* __restrict__ wr_w, const float* __restrict__ wr_b,
                const float* __restrict__ wz_w, const float* __restrict__ wz_b,
                const float* __restrict__ wh_w, const float* __restrict__ wh_b,
                const float* __restrict__ aux_w, const float* __restrict__ aux_b,
                float* __restrict__ out)
{
    __shared__ int sSeq[16][T_LEN];
    __shared__ __align__(16) float sTP[16][64];
    __shared__ __align__(16) unsigned short sHGhi[16][72], sHGlo[16][72];
    __shared__ __align__(16) unsigned short sHAhi[16][72], sHAlo[16][72];
    __shared__ __align__(16) unsigned short sRHhi[16][72], sRHlo[16][72];
    __shared__ __align__(16) unsigned short sXhi[16][72],  sXlo[16][72];
    __shared__ float sScore[2][16];
    __shared__ float sParts[16][4];

    const int tid  = threadIdx.x;
    const int wave = tid >> 6;           // 0..7
    const int lane = tid & 63;
    const int c    = lane & 15;
    const int q    = lane >> 4;
    const bool isG = (wave < 4);
    const int wg   = wave & 3;
    const int dglob = wg * 16 + c;
    const int row0 = blockIdx.x * 16;

    // ---- stage seq indices ----
    for (int i = tid; i < 16 * T_LEN; i += 512) {
        int b = i / T_LEN, t = i - b * T_LEN;
        sSeq[b][t] = seq[(row0 + b) * T_LEN + t];
    }

    // ---- fm1 ----
    if (tid < 16) {
        int b = row0 + tid;
        out[b] = user_bias[u_idx[b]] + item_bias[i_idx[b]];
    }

    // ---- target_proj (16x64 fp32), threads 0..255 ----
    if (tid < 256) {
        int b  = tid >> 4;
        int d0 = (tid & 15) * 4;
        const float* erow = item_emb + (long)i_idx[row0 + b] * 64;
        float e[64];
        #pragma unroll
        for (int k4 = 0; k4 < 16; k4++) {
            f32x4 v = *(const f32x4*)(erow + k4 * 4);
            #pragma unroll
            for (int j = 0; j < 4; j++) e[k4 * 4 + j] = v[j];
        }
        #pragma unroll
        for (int dd = 0; dd < 4; dd++) {
            int d = d0 + dd;
            const float* wrow = attn_w + d * 64;
            float s = attn_b[d];
            #pragma unroll
            for (int k4 = 0; k4 < 16; k4++) {
                f32x4 wv = *(const f32x4*)(wrow + k4 * 4);
                #pragma unroll
                for (int j = 0; j < 4; j++) s += e[k4 * 4 + j] * wv[j];
            }
            sTP[b][d] = s;
        }
    }

    // ---- zero ha exchange buffer; prime sX with x(0) (G waves) ----
    for (int i = tid; i < 16 * 72; i += 512) {
        sHAhi[0][i] = 0; sHAlo[0][i] = 0;
    }
    const int xrow = wg * 4 + (lane >> 4);   // producer row (G)
    const int xch  = lane & 15;              // 4-float chunk within row
    if (isG) {
        const float* p = item_emb + (long)seq[(row0 + xrow) * T_LEN + 0] * 64 + xch * 4;
        f32x4 v = *(const f32x4*)p;
        unsigned h01 = pack2(v[0], v[1]), h23 = pack2(v[2], v[3]);
        unsigned l01 = pack2(lo_of(v[0]), lo_of(v[1])), l23 = pack2(lo_of(v[2]), lo_of(v[3]));
        *(uint2*)&sXhi[xrow][xch * 4] = make_uint2(h01, h23);
        *(uint2*)&sXlo[xrow][xch * 4] = make_uint2(l01, l23);
    }
    __syncthreads();

    // ---- register-resident weights (bf16-hi RNE), unioned across groups ----
    bf16x8 W[12];
    if (isG) {
        #pragma unroll
        for (int g = 0; g < 3; g++)
            #pragma unroll
            for (int s = 0; s < 2; s++) {
                W[g * 2 + s]     = load_w(gw_ih + (g * 64 + dglob) * 64 + s * 32 + q * 8);
                W[6 + g * 2 + s] = load_w(gw_hh + (g * 64 + dglob) * 64 + s * 32 + q * 8);
            }
    } else {
        #pragma unroll
        for (int s = 0; s < 2; s++) {
            const int fo = dglob * 128 + s * 32 + q * 8;
            W[0 + s]  = load_w(wr_w + fo);
            W[2 + s]  = load_w(wr_w + fo + 64);
            W[4 + s]  = load_w(wz_w + fo);
            W[6 + s]  = load_w(wz_w + fo + 64);
            W[8 + s]  = load_w(wh_w + fo);
            W[10 + s] = load_w(wh_w + fo + 64);
        }
    }

    float bA, bB, bC, bD;
    if (isG) {
        bA = gb_ih[dglob] + gb_hh[dglob];
        bB = gb_ih[64 + dglob] + gb_hh[64 + dglob];
        bC = gb_ih[128 + dglob];
        bD = gb_hh[128 + dglob];
    } else {
        bA = wr_b[dglob];
        bB = wz_b[dglob];
        bC = wh_b[dglob];
        bD = 0.0f;
    }
    const float auxwc = aux_w[dglob];

    // TP as B-fragment (G only), hi/lo
    Frag tpB0, tpB1;
    if (isG) {
        tpB0 = make_frag(*(const f32x4*)&sTP[c][q * 8], *(const f32x4*)&sTP[c][q * 8 + 4]);
        tpB1 = make_frag(*(const f32x4*)&sTP[c][32 + q * 8], *(const f32x4*)&sTP[c][32 + q * 8 + 4]);
    }

    // ---- state ----
    float hst[4] = {0.f, 0.f, 0.f, 0.f};   // G: hg(t); A: ha(t-1)
    Frag fr[2];                             // G: hg frags; A: ha frags
    #pragma unroll
    for (int s = 0; s < 2; s++)
        #pragma unroll
        for (int j = 0; j < 8; j++) { fr[s].hi[j] = (__bf16)0.f; fr[s].lo[j] = (__bf16)0.f; }
    f32x4 aAH = {0.f, 0.f, 0.f, 0.f};
    float z_c[4] = {0.f, 0.f, 0.f, 0.f};

    for (int t = 0; t < T_LEN; t++) {
        f32x4 xg;         // G: x(t+1) raw (global), consumed in S1
        f32x4 aAR, aAZ;   // A: r/z preactivations, live S0 -> S1

        // ================= Section 0 =================
        Frag xA0, xA1;
        xA0.hi = *(const bf16x8*)&sXhi[c][q * 8];
        xA1.hi = *(const bf16x8*)&sXhi[c][32 + q * 8];
        xA0.lo = *(const bf16x8*)&sXlo[c][q * 8];
        xA1.lo = *(const bf16x8*)&sXlo[c][32 + q * 8];

        if (isG) {
            int tn = (t + 1 < T_LEN) ? t + 1 : t;
            xg = *(const f32x4*)(item_emb + (long)sSeq[xrow][tn] * 64 + xch * 4);

            f32x4 accR = {bA, bA, bA, bA};
            accR = mm2(xA0, W[0], accR); accR = mm2(xA1, W[1], accR);
            accR = mm2(fr[0], W[6], accR); accR = mm2(fr[1], W[7], accR);
            f32x4 accZ = {bB, bB, bB, bB};
            accZ = mm2(xA0, W[2], accZ); accZ = mm2(xA1, W[3], accZ);
            accZ = mm2(fr[0], W[8], accZ); accZ = mm2(fr[1], W[9], accZ);
            f32x4 accNX = {bC, bC, bC, bC};
            accNX = mm2(xA0, W[4], accNX); accNX = mm2(xA1, W[5], accNX);
            f32x4 accNH = {bD, bD, bD, bD};
            accNH = mm2(fr[0], W[10], accNH); accNH = mm2(fr[1], W[11], accNH);

            #pragma unroll
            for (int i = 0; i < 4; i++) {
                float r = sigf(accR[i]);
                float z = sigf(accZ[i]);
                float n = tanh_fast(accNX[i] + r * accNH[i]);
                float hn = n + z * (hst[i] - n);
                hst[i] = hn;
                int rr = q * 4 + i;
                publish(&sHGhi[rr][dglob], &sHGlo[rr][dglob], hn);
            }
        } else {
            if (t > 0) {
                Frag rh0, rh1;
                rh0.hi = *(const bf16x8*)&sRHhi[c][q * 8];
                rh1.hi = *(const bf16x8*)&sRHhi[c][32 + q * 8];
                rh0.lo = *(const bf16x8*)&sRHlo[c][q * 8];
                rh1.lo = *(const bf16x8*)&sRHlo[c][32 + q * 8];
                aAH = mm2(rh0, W[10], aAH); aAH = mm2(rh1, W[11], aAH);
                #pragma unroll
                for (int i = 0; i < 4; i++) {
                    int rr = q * 4 + i;
                    float a = sigf(sScore[(t - 1) & 1][rr]);
                    float hh = tanh_fast(aAH[i]);
                    float zz = a * z_c[i];
                    float hv = hst[i] + zz * (hh - hst[i]);
                    hst[i] = hv;
                    publish(&sHAhi[rr][dglob], &sHAlo[rr][dglob], hv);
                }
            }
            aAR = (f32x4){bA, bA, bA, bA};
            aAR = mm2(xA0, W[0], aAR); aAR = mm2(xA1, W[1], aAR);
            aAZ = (f32x4){bB, bB, bB, bB};
            aAZ = mm2(xA0, W[4], aAZ); aAZ = mm2(xA1, W[5], aAZ);
            aAH = (f32x4){bC, bC, bC, bC};
            aAH = mm2(xA0, W[8], aAH); aAH = mm2(xA1, W[9], aAH);
        }

        __syncthreads();  // b_mid

        // ================= Section 1 =================
        if (isG) {
            fr[0].hi = *(const bf16x8*)&sHGhi[c][q * 8];
            fr[1].hi = *(const bf16x8*)&sHGhi[c][32 + q * 8];
            fr[0].lo = *(const bf16x8*)&sHGlo[c][q * 8];
            fr[1].lo = *(const bf16x8*)&sHGlo[c][32 + q * 8];
            // score(t) = diag(hg(t) . tp^T) via MFMA
            f32x4 sc = {0.f, 0.f, 0.f, 0.f};
            sc = mm3(fr[0], tpB0, sc);
            sc = mm3(fr[1], tpB1, sc);
            if (wg == 0 && (c >> 2) == q) {
                int i = c & 3;
                float d = (i == 0) ? sc[0] : (i == 1) ? sc[1] : (i == 2) ? sc[2] : sc[3];
                sScore[t & 1][c] = d;
            }
            // stage x(t+1) pre-split into sX
            unsigned h01 = pack2(xg[0], xg[1]), h23 = pack2(xg[2], xg[3]);
            unsigned l01 = pack2(lo_of(xg[0]), lo_of(xg[1]));
            unsigned l23 = pack2(lo_of(xg[2]), lo_of(xg[3]));
            *(uint2*)&sXhi[xrow][xch * 4] = make_uint2(h01, h23);
            *(uint2*)&sXlo[xrow][xch * 4] = make_uint2(l01, l23);
        } else {
            fr[0].hi = *(const bf16x8*)&sHAhi[c][q * 8];
            fr[1].hi = *(const bf16x8*)&sHAhi[c][32 + q * 8];
            fr[0].lo = *(const bf16x8*)&sHAlo[c][q * 8];
            fr[1].lo = *(const bf16x8*)&sHAlo[c][32 + q * 8];
            aAR = mm2(fr[0], W[2], aAR); aAR = mm2(fr[1], W[3], aAR);
            aAZ = mm2(fr[0], W[6], aAZ); aAZ = mm2(fr[1], W[7], aAZ);
            #pragma unroll
            for (int i = 0; i < 4; i++) {
                float r = sigf(aAR[i]);
                z_c[i]  = sigf(aAZ[i]);
                float rh = r * hst[i];
                int rr = q * 4 + i;
                publish(&sRHhi[rr][dglob], &sRHlo[rr][dglob], rh);
            }
        }

        __syncthreads();  // b_end
    }

    // ---- epilogue: A finalizes ha(T-1), writes attn_vec ----
    if (!isG) {
        Frag rh0, rh1;
        rh0.hi = *(const bf16x8*)&sRHhi[c][q * 8];
        rh1.hi = *(const bf16x8*)&sRHhi[c][32 + q * 8];
        rh0.lo = *(const bf16x8*)&sRHlo[c][q * 8];
        rh1.lo = *(const bf16x8*)&sRHlo[c][32 + q * 8];
        aAH = mm2(rh0, W[10], aAH); aAH = mm2(rh1, W[11], aAH);
        #pragma unroll
        for (int i = 0; i < 4; i++) {
            int rr = q * 4 + i;
            float a = sigf(sScore[(T_LEN - 1) & 1][rr]);
            float hh = tanh_fast(aAH[i]);
            float zz = a * z_c[i];
            float hv = hst[i] + zz * (hh - hst[i]);
            out[NB + (row0 + rr) * 64 + dglob] = hv;
        }
    }

    // ---- aux_logits from hg(T-1) (G group) ----
    if (isG) {
        float pa[4];
        #pragma unroll
        for (int i = 0; i < 4; i++) pa[i] = hst[i] * auxwc;
        #pragma unroll
        for (int m = 1; m < 16; m <<= 1) {
            #pragma unroll
            for (int i = 0; i < 4; i++) pa[i] += __shfl_xor(pa[i], m, 64);
        }
        if (c == 0) {
            #pragma unroll
            for (int i = 0; i < 4; i++) sParts[q * 4 + i][wg] = pa[i];
        }
    }
    __syncthreads();
    if (tid < 16) {
        out[NB + NB * 64 + row0 + tid] =
            sParts[tid][0] + sParts[tid][1] + sParts[tid][2] + sParts[tid][3] + aux_b[0];
    }
}

extern "C" void kernel_launch(void* const* d_in, const int* in_sizes, int n_in,
                              void* d_out, int out_size, void* d_ws, size_t ws_size,
                              hipStream_t stream) {
    dien_fused<<<dim3(256), dim3(512), 0, stream>>>(
        (const int*)d_in[0],      // u_idx
        (const int*)d_in[1],      // i_idx
        (const int*)d_in[2],      // seq
        (const float*)d_in[3],    // item_emb
        (const float*)d_in[4],    // user_bias
        (const float*)d_in[5],    // item_bias
        (const float*)d_in[6],    // gru_w_ih
        (const float*)d_in[7],    // gru_b_ih
        (const float*)d_in[8],    // gru_w_hh
        (const float*)d_in[9],    // gru_b_hh
        (const float*)d_in[10],   // attn_w
        (const float*)d_in[11],   // attn_b
        (const float*)d_in[12],   // wr_w
        (const float*)d_in[13],   // wr_b
        (const float*)d_in[14],   // wz_w
        (const float*)d_in[15],   // wz_b
        (const float*)d_in[16],   // wh_w
        (const float*)d_in[17],   // wh_b
        (const float*)d_in[18],   // aux_w
        (const float*)d_in[19],   // aux_b
        (float*)d_out);
}